// Round 9
// baseline (487.373 us; speedup 1.0000x reference)
//
#include <hip/hip_runtime.h>

typedef unsigned short u16;
typedef unsigned int   u32;
typedef __attribute__((ext_vector_type(8))) short s16x8;   // 8 bf16 (4 VGPRs)
typedef __attribute__((ext_vector_type(4))) float f32x4;   // MFMA accum

#define B_   2
#define S_   2048
#define HID  1024
#define NH   16
#define N3   3072
#define M_   4096
#define C2   0.36067376022224085f   // 0.25 * log2(e)  (scale folded into log2 domain)
#define OFF2 12.0f                  // fixed stabilization offset, log2 domain

__device__ __forceinline__ u16 f2b(float f) {
  union { float f; u32 u; } v; v.f = f;
  u32 r = (v.u + 0x7FFFu + ((v.u >> 16) & 1u)) >> 16;   // RNE
  return (u16)r;
}

__device__ __forceinline__ float b2f(u16 x) {
  union { u32 u; float f; } v; v.u = (u32)x << 16;
  return v.f;
}

__device__ __forceinline__ u32 cvt_pk_bf16(float lo, float hi) {
  u32 r;
  asm("v_cvt_pk_bf16_f32 %0, %1, %2" : "=v"(r) : "v"(lo), "v"(hi));
  return r;
}

// async global->LDS, 16B per lane, wave-uniform LDS base (m97 pattern, GEMM only)
#define GLL(gp, lp)                                                          \
  __builtin_amdgcn_global_load_lds(                                          \
      (const __attribute__((address_space(1))) void*)(gp),                   \
      (__attribute__((address_space(3))) void*)(lp), 16, 0, 0)

// ---------------------------------------------------------------------------
// fp32 -> bf16 elementwise (x)
// ---------------------------------------------------------------------------
__global__ __launch_bounds__(256) void conv_bf16(const float* __restrict__ in,
                                                 u16* __restrict__ out, int n4) {
  int i = blockIdx.x * 256 + threadIdx.x;
  if (i >= n4) return;
  float4 v = ((const float4*)in)[i];
  ushort4 o = { f2b(v.x), f2b(v.y), f2b(v.z), f2b(v.w) };
  ((ushort4*)out)[i] = o;
}

// ---------------------------------------------------------------------------
// fp32 [K][N] -> bf16 [N][K] transpose (weights)
// ---------------------------------------------------------------------------
__global__ __launch_bounds__(256) void transpose_bf16(const float* __restrict__ in,
                                                      u16* __restrict__ out,
                                                      int K, int N) {
  __shared__ float T[32][33];
  const int t = threadIdx.x;
  const int k0 = blockIdx.y * 32, n0 = blockIdx.x * 32;
  {
    int r = t >> 3, c4 = (t & 7) * 4;
    float4 v = *(const float4*)(in + (size_t)(k0 + r) * N + n0 + c4);
    T[r][c4 + 0] = v.x; T[r][c4 + 1] = v.y; T[r][c4 + 2] = v.z; T[r][c4 + 3] = v.w;
  }
  __syncthreads();
  int n = t >> 3, kc = (t & 7) * 4;
  ushort4 o = { f2b(T[kc + 0][n]), f2b(T[kc + 1][n]), f2b(T[kc + 2][n]), f2b(T[kc + 3][n]) };
  *(ushort4*)(out + (size_t)(n0 + n) * K + k0 + kc) = o;
}

// ---------------------------------------------------------------------------
// zero the z accumulator (65536 f32)
// ---------------------------------------------------------------------------
__global__ __launch_bounds__(256) void zero_f32(float* __restrict__ p) {
  ((float4*)p)[blockIdx.x * 256 + threadIdx.x] = (float4){0.f, 0.f, 0.f, 0.f};
}

// ---------------------------------------------------------------------------
// bf16 kqv V-part -> Vt[bh][d=64][s=2048], scaled by 1/z_s (softmax fold)
// ---------------------------------------------------------------------------
__global__ __launch_bounds__(256) void v_transpose_scaled(const u16* __restrict__ kqv,
                                                          const float* __restrict__ zacc,
                                                          u16* __restrict__ Vtg) {
  __shared__ u16 Vl[64 * 66];
  const int t = threadIdx.x;
  const int bh = blockIdx.y, b = bh >> 4, h = bh & 15;
  const int s0 = blockIdx.x * 64;
  const u16* src = kqv + (size_t)b * S_ * N3 + 2 * HID + h * 64;
  #pragma unroll
  for (int cc = 0; cc < 2; ++cc) {
    int c = t + cc * 256;
    int row = c >> 3, dc = c & 7;
    uint4 v = *(const uint4*)(src + (size_t)(s0 + row) * N3 + dc * 8);
    u32* pe = (u32*)&v;
    #pragma unroll
    for (int e = 0; e < 4; ++e)
      *(u32*)(Vl + row * 66 + dc * 8 + 2 * e) = pe[e];
  }
  __syncthreads();
  #pragma unroll
  for (int cc = 0; cc < 2; ++cc) {
    int c = t + cc * 256;
    int d = c >> 3, sc = c & 7;
    float4 za = *(const float4*)(zacc + (size_t)bh * S_ + s0 + sc * 8);
    float4 zb = *(const float4*)(zacc + (size_t)bh * S_ + s0 + sc * 8 + 4);
    float zi[8] = { za.x, za.y, za.z, za.w, zb.x, zb.y, zb.z, zb.w };
    u16 tmp[8];
    #pragma unroll
    for (int j = 0; j < 8; ++j)
      tmp[j] = f2b(b2f(Vl[(sc * 8 + j) * 66 + d]) / zi[j]);
    *(uint4*)(Vtg + ((size_t)bh * 64 + d) * S_ + s0 + sc * 8) = *(uint4*)tmp;
  }
}

// ---------------------------------------------------------------------------
// bf16 MFMA GEMM (m97 structure): C[M,N] = A[M,K] @ Bt[N,K]^T + bias
// ---------------------------------------------------------------------------
template <int OUTBF16>
__global__ __launch_bounds__(256) void gemm_bf16(const u16* __restrict__ A,
                                                 const u16* __restrict__ Bt,
                                                 const float* __restrict__ bias,
                                                 void* __restrict__ Cout,
                                                 int M, int N, int K) {
  __shared__ u16 Al[128 * 32];
  __shared__ u16 Bl[128 * 32];
  const int t = threadIdx.x, lane = t & 63, w = t >> 6;
  const int m0 = blockIdx.y * 128, n0 = blockIdx.x * 128;
  const int wm = (w >> 1) * 64, wn = (w & 1) * 64;
  const int r = lane & 15, g = lane >> 4;

  f32x4 acc[4][4];
  #pragma unroll
  for (int i = 0; i < 4; ++i)
    #pragma unroll
    for (int j = 0; j < 4; ++j) acc[i][j] = (f32x4){0.f, 0.f, 0.f, 0.f};

  const int c0 = (w << 7) + lane, c1 = c0 + 64;
  const int ar0 = c0 >> 2, ak0 = (c0 & 3) << 3;
  const int ar1 = c1 >> 2, ak1 = (c1 & 3) << 3;

  for (int k0 = 0; k0 < K; k0 += 32) {
    __syncthreads();
    GLL(A  + (size_t)(m0 + ar0) * K + k0 + ak0, Al + (w << 10));
    GLL(A  + (size_t)(m0 + ar1) * K + k0 + ak1, Al + (w << 10) + 512);
    GLL(Bt + (size_t)(n0 + ar0) * K + k0 + ak0, Bl + (w << 10));
    GLL(Bt + (size_t)(n0 + ar1) * K + k0 + ak1, Bl + (w << 10) + 512);
    __syncthreads();

    s16x8 af[4], bf[4];
    #pragma unroll
    for (int mf = 0; mf < 4; ++mf)
      af[mf] = *(const s16x8*)(Al + (wm + mf * 16 + r) * 32 + g * 8);
    #pragma unroll
    for (int nf = 0; nf < 4; ++nf)
      bf[nf] = *(const s16x8*)(Bl + (wn + nf * 16 + r) * 32 + g * 8);
    #pragma unroll
    for (int mf = 0; mf < 4; ++mf)
      #pragma unroll
      for (int nf = 0; nf < 4; ++nf)
        acc[mf][nf] = __builtin_amdgcn_mfma_f32_16x16x32_bf16(af[mf], bf[nf], acc[mf][nf], 0, 0, 0);
  }

  float bv[4];
  #pragma unroll
  for (int nf = 0; nf < 4; ++nf) bv[nf] = bias[n0 + wn + nf * 16 + r];

  #pragma unroll
  for (int mf = 0; mf < 4; ++mf)
    #pragma unroll
    for (int nf = 0; nf < 4; ++nf)
      #pragma unroll
      for (int q = 0; q < 4; ++q) {
        float o = acc[mf][nf][q] + bv[nf];
        size_t idx = (size_t)(m0 + wm + mf * 16 + 4 * g + q) * N + (n0 + wn + nf * 16 + r);
        if (OUTBF16) ((u16*)Cout)[idx] = f2b(o);
        else         ((float*)Cout)[idx] = o;
      }
}

// ---------------------------------------------------------------------------
// Stats (split over n): zacc[s] += sum_{n in half} exp2(C2*K_s.Q_n - OFF2)
// NO LDS, NO barriers: K frags hoisted to registers; Q frags read directly
// from global (wave-independent rows -> L1/L2-served, 4x cross-wave reuse).
// grid (32 s-tiles, 32 bh, 2 halves).
// ---------------------------------------------------------------------------
__global__ __launch_bounds__(256, 6) void attn_stats(const u16* __restrict__ kqv,
                                                     float* __restrict__ zacc) {
  const int t = threadIdx.x, lane = t & 63, w = t >> 6;
  const int bh = blockIdx.y, b = bh >> 4, h = bh & 15;
  const int s0 = blockIdx.x * 64;
  const int nbase = blockIdx.z * (S_ / 2);
  const u16* base = kqv + (size_t)b * S_ * N3;
  const int r = lane & 15, g = lane >> 4;

  const u16* kp = base + (size_t)(s0 + w * 16 + r) * N3 + h * 64 + g * 8;
  const s16x8 ka0 = *(const s16x8*)(kp);
  const s16x8 ka1 = *(const s16x8*)(kp + 32);

  const u16* qp = base + (size_t)(nbase + r) * N3 + HID + h * 64 + g * 8;
  float z[4] = {0.f, 0.f, 0.f, 0.f};

  for (int nt = 0; nt < 16; ++nt) {
    #pragma unroll
    for (int nf = 0; nf < 4; ++nf) {
      const u16* q = qp + (size_t)(nt * 64 + nf * 16) * N3;
      s16x8 qb0 = *(const s16x8*)(q);
      s16x8 qb1 = *(const s16x8*)(q + 32);
      f32x4 sc = (f32x4){0.f, 0.f, 0.f, 0.f};
      __builtin_amdgcn_s_setprio(1);
      sc = __builtin_amdgcn_mfma_f32_16x16x32_bf16(ka0, qb0, sc, 0, 0, 0);
      sc = __builtin_amdgcn_mfma_f32_16x16x32_bf16(ka1, qb1, sc, 0, 0, 0);
      __builtin_amdgcn_s_setprio(0);
      #pragma unroll
      for (int q2 = 0; q2 < 4; ++q2)
        z[q2] += exp2f(fmaf(sc[q2], C2, -OFF2));
    }
  }
  #pragma unroll
  for (int m = 1; m <= 8; m <<= 1)
    #pragma unroll
    for (int q2 = 0; q2 < 4; ++q2) z[q2] += __shfl_xor(z[q2], m);
  if (r == 0)
    #pragma unroll
    for (int q2 = 0; q2 < 4; ++q2)
      atomicAdd(zacc + (size_t)bh * S_ + s0 + w * 16 + 4 * g + q2, z[q2]);
}

// ---------------------------------------------------------------------------
// PV pass (split over s): pout[n,d] = sum_{s in half} exp2(C2*Q.K - OFF2)*V'[s,d]
// (1/z_s pre-folded into V'.)  K and V' fragments read DIRECTLY from global
// (wave-independent rows -> L1/L2-served); only P lives in LDS (wave-private
// rows -> NO barriers anywhere). P swizzle r6/r8-proven.
// grid (32 n-tiles, 32 bh, 2 halves).
// ---------------------------------------------------------------------------
__global__ __launch_bounds__(256, 4) void attn_pv(const u16* __restrict__ kqv,
                                                  const u16* __restrict__ Vtg,
                                                  u16* __restrict__ p0,
                                                  u16* __restrict__ p1) {
  __shared__ u16 Pl[64 * 72];     // P tile only (wave-private rows)
  const int t = threadIdx.x, lane = t & 63, w = t >> 6;
  const int bh = blockIdx.y, b = bh >> 4, h = bh & 15;
  const int n0 = blockIdx.x * 64;
  const int sbase = blockIdx.z * 16;   // chunk index base
  const u16* base = kqv + (size_t)b * S_ * N3;
  const u16* vtb  = Vtg + (size_t)bh * 64 * S_;
  const int r = lane & 15, g = lane >> 4;

  const u16* qp = base + (size_t)(n0 + w * 16 + r) * N3 + HID + h * 64 + g * 8;
  const s16x8 qa0 = *(const s16x8*)(qp);
  const s16x8 qa1 = *(const s16x8*)(qp + 32);

  const u16* kp = base + (size_t)r * N3 + h * 64 + g * 8;   // + (s0+sf*16)*N3
  const u16* vp = vtb + (size_t)r * S_ + g * 8;             // + df*16*S_ + s0 + ks*32

  f32x4 oacc[4];
  #pragma unroll
  for (int i = 0; i < 4; ++i) oacc[i] = (f32x4){0.f, 0.f, 0.f, 0.f};

  for (int st = 0; st < 16; ++st) {
    const int s0 = (sbase + st) * 64;

    // scoreT[n][s] from direct-global K frags -> weights -> P (swizzled)
    #pragma unroll
    for (int sf = 0; sf < 4; ++sf) {
      const u16* k = kp + (size_t)(s0 + sf * 16) * N3;
      s16x8 kb0 = *(const s16x8*)(k);
      s16x8 kb1 = *(const s16x8*)(k + 32);
      f32x4 sc = (f32x4){0.f, 0.f, 0.f, 0.f};
      __builtin_amdgcn_s_setprio(1);
      sc = __builtin_amdgcn_mfma_f32_16x16x32_bf16(qa0, kb0, sc, 0, 0, 0);
      sc = __builtin_amdgcn_mfma_f32_16x16x32_bf16(qa1, kb1, sc, 0, 0, 0);
      __builtin_amdgcn_s_setprio(0);
      float pp0 = exp2f(fmaf(sc[0], C2, -OFF2));
      float pp1 = exp2f(fmaf(sc[1], C2, -OFF2));
      float pp2 = exp2f(fmaf(sc[2], C2, -OFF2));
      float pp3 = exp2f(fmaf(sc[3], C2, -OFF2));
      u32 pk01 = cvt_pk_bf16(pp0, pp1);
      u32 pk23 = cvt_pk_bf16(pp2, pp3);
      int pc = (sf * 2 + (r >> 3)) ^ (2 * g);
      int pbase = (w * 16 + 4 * g) * 72 + pc * 8 + (r & 7);
      Pl[pbase]       = (u16)pk01;           // row +0
      Pl[pbase + 72]  = (u16)(pk01 >> 16);   // row +1
      Pl[pbase + 144] = (u16)pk23;           // row +2
      Pl[pbase + 216] = (u16)(pk23 >> 16);   // row +3
    }
    // PV: P rows wave-private (same-wave lgkm ordering); V' frags direct-global
    __builtin_amdgcn_s_setprio(1);
    #pragma unroll
    for (int ks = 0; ks < 2; ++ks) {
      s16x8 pa = *(const s16x8*)(Pl + (w * 16 + r) * 72 +
                                 ((ks * 4 + g) ^ (2 * (r >> 2))) * 8);
      #pragma unroll
      for (int df = 0; df < 4; ++df) {
        s16x8 vb = *(const s16x8*)(vp + (size_t)(df * 16) * S_ + s0 + ks * 32);
        oacc[df] = __builtin_amdgcn_mfma_f32_16x16x32_bf16(pa, vb, oacc[df], 0, 0, 0);
      }
    }
    __builtin_amdgcn_s_setprio(0);
  }

  u16* dst = blockIdx.z ? p1 : p0;
  #pragma unroll
  for (int df = 0; df < 4; ++df)
    #pragma unroll
    for (int q = 0; q < 4; ++q)
      dst[(size_t)(b * S_ + n0 + w * 16 + 4 * g + q) * HID + h * 64 + df * 16 + r] =
          f2b(oacc[df][q]);
}

// ---------------------------------------------------------------------------
// combine bf16 partials: p0 += p1 (elementwise), in place on p0
// ---------------------------------------------------------------------------
__global__ __launch_bounds__(256) void combine_halves(u16* __restrict__ p0,
                                                      const u16* __restrict__ p1) {
  int i = blockIdx.x * 256 + threadIdx.x;
  uint4 a = ((const uint4*)p0)[i];
  uint4 bq = ((const uint4*)p1)[i];
  const u16* ae = (const u16*)&a;
  const u16* be = (const u16*)&bq;
  u16 o[8];
  #pragma unroll
  for (int j = 0; j < 8; ++j) o[j] = f2b(b2f(ae[j]) + b2f(be[j]));
  ((uint4*)p0)[i] = *(uint4*)o;
}

// ---------------------------------------------------------------------------
extern "C" void kernel_launch(void* const* d_in, const int* in_sizes, int n_in,
                              void* d_out, int out_size, void* d_ws, size_t ws_size,
                              hipStream_t stream) {
  const float* x     = (const float*)d_in[0];
  const float* kqv_w = (const float*)d_in[1];
  const float* kqv_b = (const float*)d_in[2];
  const float* ff_w  = (const float*)d_in[3];
  const float* ff_b  = (const float*)d_in[4];
  float* out = (float*)d_out;

  u16* xb    = (u16*)d_ws;                         // 4096*1024  (pv partial1 later)
  u16* w1t   = xb   + (size_t)M_ * HID;            // 3072*1024
  u16* w2t   = w1t  + (size_t)N3 * HID;            // 1024*1024
  u16* kqvb  = w2t  + (size_t)HID * HID;           // 4096*3072
  u16* vtg   = kqvb + (size_t)M_ * N3;             // 32*64*2048
  float* zac = (float*)(vtg + (size_t)B_ * NH * 64 * S_);   // 32*2048 f32
  u16* attnb = (u16*)(zac + (size_t)B_ * NH * S_); // 4096*1024 (pv partial0)
  // total ~56.3 MB

  dim3 blk(256);
  conv_bf16<<<dim3(M_ * HID / 4 / 256), blk, 0, stream>>>(x, xb, M_ * HID / 4);
  transpose_bf16<<<dim3(N3 / 32, HID / 32), blk, 0, stream>>>(kqv_w, w1t, HID, N3);
  transpose_bf16<<<dim3(HID / 32, HID / 32), blk, 0, stream>>>(ff_w, w2t, HID, HID);

  gemm_bf16<1><<<dim3(N3 / 128, M_ / 128), blk, 0, stream>>>(
      xb, w1t, kqv_b, kqvb, M_, N3, HID);
  // xb is dead from here until attn_pv writes partial1 into it.

  zero_f32<<<dim3(B_ * NH * S_ / 4 / 256), blk, 0, stream>>>(zac);
  attn_stats<<<dim3(S_ / 64, B_ * NH, 2), blk, 0, stream>>>(kqvb, zac);
  v_transpose_scaled<<<dim3(S_ / 64, B_ * NH), blk, 0, stream>>>(kqvb, zac, vtg);
  attn_pv<<<dim3(S_ / 64, B_ * NH, 2), blk, 0, stream>>>(kqvb, vtg, attnb, xb);
  combine_halves<<<dim3(M_ * HID / 8 / 256), blk, 0, stream>>>(attnb, xb);

  gemm_bf16<0><<<dim3(HID / 128, M_ / 128), blk, 0, stream>>>(
      attnb, w2t, ff_b, out, M_, HID, HID);
}